// Round 11
// baseline (684.263 us; speedup 1.0000x reference)
//
#include <hip/hip_runtime.h>

#define BB 128
#define TE 2048
#define UU 256
#define IN_DIM 256
#define MC 32   // rows per chunk
#define NCH 8   // chunks per block
#define GPB 8   // blocks per batch row (TE / (MC*NCH))

typedef float f32x4 __attribute__((ext_vector_type(4)));
typedef __fp16 f16x2 __attribute__((ext_vector_type(2)));   // cvt_pkrtz return type
typedef _Float16 f16x8 __attribute__((ext_vector_type(8)));

__device__ __forceinline__ float fast_tanh(float x) {
  float e = __expf(2.f * x);
  return 1.f - 2.f / (e + 1.f);
}
__device__ __forceinline__ float fast_sigmoid(float x) {
  return 1.f / (1.f + __expf(-x));
}
// LDS-only barrier: drains ds ops, does NOT drain vmcnt (keeps global prefetch in flight)
__device__ __forceinline__ void bar_lds() {
  asm volatile("s_waitcnt lgkmcnt(0)" ::: "memory");
  __builtin_amdgcn_s_barrier();
}

// ---- prep: addvec = h_tm@W_a + b_a (blocks 0..127); UhT2 = f16 frag-major U_a (blocks 128..159)
// UhT2 layout: frag (ks,lg) for MFMA B: 16B at ((ks*4+lg)*256 + n)*8 halves
__global__ __launch_bounds__(256) void prep_kernel(
    const float* __restrict__ h_tm, const float* __restrict__ W_a,
    const float* __restrict__ b_a, const float* __restrict__ U_a,
    float* __restrict__ addvec, _Float16* __restrict__ UhT2) {
  int t = threadIdx.x;
  if (blockIdx.x < BB) {
    int bi = blockIdx.x;
    __shared__ float hL[UU];
    hL[t] = h_tm[bi * UU + t];
    __syncthreads();
    float s = b_a[t];
    for (int e = 0; e < UU; ++e) s += hL[e] * W_a[e * UU + t];
    addvec[bi * UU + t] = s;
  } else {
    int b2 = blockIdx.x - BB;  // 0..31 -> k0 = b2*8
    int n = t;
    union { f16x8 v; _Float16 h[8]; } pk;
#pragma unroll
    for (int e = 0; e < 8; ++e) pk.h[e] = (_Float16)U_a[(b2 * 8 + e) * UU + n];
    *(f16x8*)(UhT2 + ((b2 * UU + n) << 3)) = pk.v;
  }
}

// ---- main: f16 LDS X tile (swizzled), dbuf, cvt at staging, B from L2 per ks.
// 4 blocks/CU (LDS 34.6KB), VGPR<=128 via launch_bounds -> 16 waves/CU.
__global__ __launch_bounds__(256, 4) void attn_main(
    const float* __restrict__ x_seq, const float* __restrict__ V_a,
    const _Float16* __restrict__ UhT2, const float* __restrict__ addvec,
    float* __restrict__ numw, float* __restrict__ denw) {
  __shared__ __align__(16) _Float16 Xh[2][MC * UU];  // 2 x 16 KB, swz half-idx ^= (row&7)<<3
  __shared__ float avL[UU], vaL[UU];
  __shared__ float wsum[4][MC];
  __shared__ float eL[MC];

  const int tid = threadIdx.x;
  const int bi = blockIdx.x >> 3;
  const int g = blockIdx.x & 7;
  const float* xc = x_seq + (size_t)(bi * TE + g * (MC * NCH)) * UU;

  const int w = tid >> 6, l = tid & 63, lr = l & 15, lg = l >> 4;

  // issue chunk-0 global loads (held in regs)
  f32x4 st[8];
#pragma unroll
  for (int j = 0; j < 8; ++j) st[j] = *(const f32x4*)(xc + (size_t)(j * 256 + tid) * 4);

  avL[tid] = addvec[bi * UU + tid];
  vaL[tid] = V_a[tid];

  // stage chunk0 -> buf0 (cvt f32->f16, swizzled b64 writes), then issue chunk1
  {
    _Float16* B0 = &Xh[0][0];
#pragma unroll
    for (int j = 0; j < 8; ++j) {
      int row = j * 4 + w;
      union { unsigned long long u; f16x2 p[2]; } pk;
      pk.p[0] = __builtin_amdgcn_cvt_pkrtz(st[j].x, st[j].y);
      pk.p[1] = __builtin_amdgcn_cvt_pkrtz(st[j].z, st[j].w);
      *(unsigned long long*)(B0 + (row << 8) + ((l * 4) ^ ((row & 7) << 3))) = pk.u;
    }
  }
#pragma unroll
  for (int j = 0; j < 8; ++j)
    st[j] = *(const f32x4*)(xc + (size_t)(MC * UU) + (size_t)(j * 256 + tid) * 4);
  bar_lds();

  float num_acc = 0.f, den_acc = 0.f;
  for (int i = 0; i < NCH; ++i) {
    const _Float16* Xc = &Xh[i & 1][0];
    f32x4 acc[2][4];
#pragma unroll
    for (int mi = 0; mi < 2; ++mi)
#pragma unroll
      for (int ni = 0; ni < 4; ++ni) acc[mi][ni] = (f32x4)0.f;

#pragma unroll
    for (int ks = 0; ks < 8; ++ks) {
      // B fragments from L2-resident UhT2 (16B coalesced per 16-lane group)
      f16x8 Bf[4];
#pragma unroll
      for (int ni = 0; ni < 4; ++ni) {
        int n = w * 64 + ni * 16 + lr;
        Bf[ni] = *(const f16x8*)(UhT2 + (((ks * 4 + lg) * UU + n) << 3));
      }
      // A fragments straight from LDS (one b128 each)
      f16x8 a[2];
#pragma unroll
      for (int mi = 0; mi < 2; ++mi) {
        int row = mi * 16 + lr;
        a[mi] = *(const f16x8*)(Xc + (row << 8) +
                                ((ks * 32 + lg * 8) ^ ((row & 7) << 3)));
      }
#pragma unroll
      for (int mi = 0; mi < 2; ++mi)
#pragma unroll
        for (int ni = 0; ni < 4; ++ni)
          acc[mi][ni] = __builtin_amdgcn_mfma_f32_16x16x32_f16(a[mi], Bf[ni],
                                                               acc[mi][ni], 0, 0, 0);
    }

    // epilogue: et rows for this chunk
    float psum[2][4];
#pragma unroll
    for (int mi = 0; mi < 2; ++mi)
#pragma unroll
      for (int r = 0; r < 4; ++r) psum[mi][r] = 0.f;
#pragma unroll
    for (int ni = 0; ni < 4; ++ni) {
      int n = w * 64 + ni * 16 + lr;
      float av = avL[n], va = vaL[n];
#pragma unroll
      for (int mi = 0; mi < 2; ++mi)
#pragma unroll
        for (int r = 0; r < 4; ++r)
          psum[mi][r] += fast_tanh(acc[mi][ni][r] + av) * va;
    }
#pragma unroll
    for (int off = 1; off < 16; off <<= 1)
#pragma unroll
      for (int mi = 0; mi < 2; ++mi)
#pragma unroll
        for (int r = 0; r < 4; ++r) psum[mi][r] += __shfl_xor(psum[mi][r], off, 64);
    if (lr == 0) {
#pragma unroll
      for (int mi = 0; mi < 2; ++mi)
#pragma unroll
        for (int r = 0; r < 4; ++r) wsum[w][mi * 16 + lg * 4 + r] = psum[mi][r];
    }
    bar_lds();
    if (tid < MC) {
      float et = wsum[0][tid] + wsum[1][tid] + wsum[2][tid] + wsum[3][tid];
      eL[tid] = __expf(et);  // unnormalized, matches reference
    }
    bar_lds();

    // num/den accumulation (f16 X from LDS; eL broadcast). 2B reads, 2 lanes/bank = free.
#pragma unroll 8
    for (int m = 0; m < MC; ++m) {
      float e = eL[m];
      num_acc += e * (float)Xc[(m << 8) + (tid ^ ((m & 7) << 3))];
      den_acc += e;
    }

    if (i < NCH - 1) {
      _Float16* Bn = &Xh[(i + 1) & 1][0];
#pragma unroll
      for (int j = 0; j < 8; ++j) {
        int row = j * 4 + w;
        union { unsigned long long u; f16x2 p[2]; } pk;
        pk.p[0] = __builtin_amdgcn_cvt_pkrtz(st[j].x, st[j].y);
        pk.p[1] = __builtin_amdgcn_cvt_pkrtz(st[j].z, st[j].w);
        *(unsigned long long*)(Bn + (row << 8) + ((l * 4) ^ ((row & 7) << 3))) = pk.u;
      }
      if (i < NCH - 2) {
        const float* src = xc + (size_t)(i + 2) * (MC * UU);
#pragma unroll
        for (int j = 0; j < 8; ++j) st[j] = *(const f32x4*)(src + (size_t)(j * 256 + tid) * 4);
      }
      bar_lds();
    }
  }
  numw[(bi * GPB + g) * UU + tid] = num_acc;
  if (tid == 0) denw[bi * GPB + g] = den_acc;
}

// ---- finalize: v1 256-thread form (known-good config)
__global__ __launch_bounds__(256) void finalize_kernel(
    const float* __restrict__ inputs, const float* __restrict__ h_tm,
    const float* __restrict__ numw, const float* __restrict__ denw,
    const float* __restrict__ C_z, const float* __restrict__ W_z,
    const float* __restrict__ b_z, const float* __restrict__ C_r,
    const float* __restrict__ W_r, const float* __restrict__ b_r,
    const float* __restrict__ C_p, const float* __restrict__ U_p,
    const float* __restrict__ b_p, float* __restrict__ out) {
  int bi = blockIdx.x, t = threadIdx.x;
  __shared__ float hL[UU], ciL[IN_DIM + UU], rhL[UU];
  float ns = 0.f;
#pragma unroll
  for (int c = 0; c < GPB; ++c) ns += numw[(bi * GPB + c) * UU + t];
  float ds = 0.f;
#pragma unroll
  for (int c = 0; c < GPB; ++c) ds += denw[bi * GPB + c];
  ciL[IN_DIM + t] = ns / ds;          // context
  ciL[t] = inputs[bi * IN_DIM + t];   // inputs
  hL[t] = h_tm[bi * UU + t];
  __syncthreads();

  float z = b_z[t], r = b_r[t], p = b_p[t];
  for (int e = 0; e < UU; ++e) {
    float h = hL[e];
    z += h * W_z[e * UU + t];
    r += h * W_r[e * UU + t];
  }
  for (int e = 0; e < IN_DIM + UU; ++e) {
    float cv = ciL[e];
    z += cv * C_z[e * UU + t];
    r += cv * C_r[e * UU + t];
    p += cv * C_p[e * UU + t];
  }
  z = fast_sigmoid(z);
  r = fast_sigmoid(r);
  rhL[t] = r * hL[t];
  __syncthreads();
  for (int e = 0; e < UU; ++e) p += rhL[e] * U_p[e * UU + t];
  float th = fast_tanh(p);
  out[bi * UU + t] = (1.f - z) * hL[t] + z * th;
}

extern "C" void kernel_launch(void* const* d_in, const int* in_sizes, int n_in,
                              void* d_out, int out_size, void* d_ws, size_t ws_size,
                              hipStream_t stream) {
  const float* inputs = (const float*)d_in[0];
  const float* h_tm = (const float*)d_in[1];
  const float* x_seq = (const float*)d_in[2];
  const float* V_a = (const float*)d_in[3];
  const float* W_a = (const float*)d_in[4];
  const float* U_a = (const float*)d_in[5];
  const float* b_a = (const float*)d_in[6];
  const float* C_z = (const float*)d_in[7];
  const float* W_z = (const float*)d_in[8];
  const float* b_z = (const float*)d_in[9];
  const float* C_r = (const float*)d_in[10];
  const float* W_r = (const float*)d_in[11];
  const float* b_r = (const float*)d_in[12];
  const float* C_p = (const float*)d_in[13];
  const float* U_p = (const float*)d_in[14];
  const float* b_p = (const float*)d_in[15];

  // ws: UhT2 f16 [32][256][8] (128KB) | addvec f32 (128KB) | numw f32 [128][8][256] (1MB) | denw [128][8]
  _Float16* UhT2 = (_Float16*)d_ws;
  float* addvec = (float*)((char*)d_ws + 131072);
  float* numw = (float*)((char*)d_ws + 262144);
  float* denw = (float*)((char*)d_ws + 262144 + 1048576);
  float* out = (float*)d_out;

  prep_kernel<<<BB + 32, 256, 0, stream>>>(h_tm, W_a, b_a, U_a, addvec, UhT2);
  attn_main<<<BB * GPB, 256, 0, stream>>>(x_seq, V_a, UhT2, addvec, numw, denw);
  finalize_kernel<<<BB, 256, 0, stream>>>(inputs, h_tm, numw, denw, C_z, W_z, b_z,
                                          C_r, W_r, b_r, C_p, U_p, b_p, out);
}